// Round 1
// baseline (517.904 us; speedup 1.0000x reference)
//
#include <hip/hip_runtime.h>

// QJLKeyCache: out = softmax_rows(EST * norms[n] * (Q @ S^T) @ K^T)
// B=2048, D=128, M=256, NKEYS=32768.
// Strategy: fp16 MFMA GEMM (keys are +-1, exact in fp16; proj rounding ~2^-12
// keeps logit error ~0.003 << 2e-2 threshold). Flash-style 2-pass softmax:
// pass1 GEMM -> per-(row, colblock) (max, sumexp) stats; combine -> per-row
// (M, 1/L); pass2 GEMM recompute -> write exp(s-M)/L directly. Avoids 512MB
// of score-matrix traffic at the cost of one extra ~35us GEMM.

#define NB 2048
#define DD 128
#define MM 256
#define NK 32768
// sqrt(pi/2)/256
#define EST_CONST 4.8957583489668673e-03f

typedef _Float16 half8 __attribute__((ext_vector_type(8)));
typedef _Float16 half4v __attribute__((ext_vector_type(4)));
typedef float floatx4 __attribute__((ext_vector_type(4)));

__device__ __forceinline__ void async16(const void* g, void* l) {
    __builtin_amdgcn_global_load_lds(
        (const __attribute__((address_space(1))) unsigned int*)g,
        (__attribute__((address_space(3))) unsigned int*)l,
        16, 0, 0);
}

// K1: proj[b][m] = sum_d query[b][d]*sketch[m][d], stored fp16.
// One block per query row; query row staged in LDS; sketch (128KB) L2-resident.
__global__ void proj_kernel(const float* __restrict__ query,
                            const float* __restrict__ sketch,
                            _Float16* __restrict__ proj) {
    __shared__ float q[DD];
    const int b = blockIdx.x;
    const int t = threadIdx.x;
    if (t < DD) q[t] = query[b * DD + t];
    __syncthreads();
    const float* srow = sketch + t * DD;   // t = m in [0,256)
    float acc = 0.f;
#pragma unroll
    for (int d = 0; d < DD; d += 4) {
        float4 s4 = *(const float4*)(srow + d);
        acc += s4.x * q[d] + s4.y * q[d + 1] + s4.z * q[d + 2] + s4.w * q[d + 3];
    }
    proj[b * MM + t] = (_Float16)acc;
}

// K2: cached_keys fp32 (+-1) -> fp16 (exact).
__global__ void cvt_keys(const float* __restrict__ keys, _Float16* __restrict__ kh) {
    const int i = blockIdx.x * 256 + threadIdx.x;   // one float4 per thread
    float4 v = ((const float4*)keys)[i];
    half4v h;
    h.x = (_Float16)v.x; h.y = (_Float16)v.y; h.z = (_Float16)v.z; h.w = (_Float16)v.w;
    ((half4v*)kh)[i] = h;
}

// GEMM: C[b][n] = sum_m A[b][m] * Bt[n][m], 128x128 tile, BK=32, fp16 MFMA.
// MODE 0: epilogue computes per-(row, colblock) max & sumexp -> stats (layout
//         [colblock][row] for coalesced combine).
// MODE 1: epilogue writes out = exp(s - rowM)*rowRcpL.
template <int MODE>
__global__ __launch_bounds__(256)
void gemm_kernel(const _Float16* __restrict__ A,    // [2048][256]
                 const _Float16* __restrict__ Bt,   // [32768][256]
                 const float* __restrict__ key_norms,
                 float* __restrict__ stats_max,     // [256][2048]
                 float* __restrict__ stats_sum,     // [256][2048]
                 const float* __restrict__ rowM,
                 const float* __restrict__ rowRcpL,
                 float* __restrict__ out) {
    __shared__ __align__(16) _Float16 sA[128 * 32];
    __shared__ __align__(16) _Float16 sB[128 * 32];
    __shared__ float red[128][2];
    __shared__ float redS[128][2];

    const int tid  = threadIdx.x;
    const int wave = tid >> 6;
    const int lane = tid & 63;
    const int quad = lane >> 4;
    const int lc   = lane & 15;
    const int wr   = wave >> 1;   // wave row (0/1) -> 64-row strip
    const int wc   = wave & 1;    // wave col (0/1) -> 64-col strip
    const int rowBase = blockIdx.y * 128;
    const int colBase = blockIdx.x * 128;

    floatx4 acc[4][4];
#pragma unroll
    for (int i = 0; i < 4; i++)
#pragma unroll
        for (int j = 0; j < 4; j++) acc[i][j] = (floatx4){0.f, 0.f, 0.f, 0.f};

    // Staging: chunk c (16B) -> LDS bytes [c*16, c*16+16) = row c>>2, k-seg c&3.
    // Wave-uniform base + lane*16 matches global_load_lds semantics.
    const int c0 = tid, c1 = tid + 256;
    const _Float16* gA0 = A + (rowBase + (c0 >> 2)) * MM + (c0 & 3) * 8;
    const _Float16* gA1 = A + (rowBase + (c1 >> 2)) * MM + (c1 & 3) * 8;
    const _Float16* gB0 = Bt + (colBase + (c0 >> 2)) * MM + (c0 & 3) * 8;
    const _Float16* gB1 = Bt + (colBase + (c1 >> 2)) * MM + (c1 & 3) * 8;

    for (int k0 = 0; k0 < MM; k0 += 32) {
        __syncthreads();   // previous iter's ds_reads done before overwrite
        async16(gA0 + k0, &sA[c0 * 8]);
        async16(gA1 + k0, &sA[c1 * 8]);
        async16(gB0 + k0, &sB[c0 * 8]);
        async16(gB1 + k0, &sB[c1 * 8]);
        __syncthreads();   // compiler emits vmcnt(0) drain before barrier

        half8 a[4], b[4];
#pragma unroll
        for (int i = 0; i < 4; i++)
            a[i] = *(const half8*)&sA[(wr * 64 + i * 16 + lc) * 32 + quad * 8];
#pragma unroll
        for (int j = 0; j < 4; j++)
            b[j] = *(const half8*)&sB[(wc * 64 + j * 16 + lc) * 32 + quad * 8];
#pragma unroll
        for (int i = 0; i < 4; i++)
#pragma unroll
            for (int j = 0; j < 4; j++)
                acc[i][j] = __builtin_amdgcn_mfma_f32_16x16x32_f16(a[i], b[j], acc[i][j], 0, 0, 0);
    }

    // scale: s = EST_CONST * key_norms[col] * inner  (norms kept fp32 here)
    float cscale[4];
#pragma unroll
    for (int j = 0; j < 4; j++)
        cscale[j] = EST_CONST * key_norms[colBase + wc * 64 + j * 16 + lc];
#pragma unroll
    for (int i = 0; i < 4; i++)
#pragma unroll
        for (int j = 0; j < 4; j++)
#pragma unroll
            for (int r = 0; r < 4; r++) acc[i][j][r] *= cscale[j];

    if (MODE == 0) {
        // per-row (over this block's 128 cols) max
        float mloc[4][4];
#pragma unroll
        for (int i = 0; i < 4; i++)
#pragma unroll
            for (int r = 0; r < 4; r++) {
                float mx = fmaxf(fmaxf(acc[i][0][r], acc[i][1][r]),
                                 fmaxf(acc[i][2][r], acc[i][3][r]));
#pragma unroll
                for (int d = 1; d < 16; d <<= 1) mx = fmaxf(mx, __shfl_xor(mx, d, 64));
                if (lc == 0) red[wr * 64 + i * 16 + quad * 4 + r][wc] = mx;
            }
        __syncthreads();
        // per-row sumexp with block-local max
#pragma unroll
        for (int i = 0; i < 4; i++)
#pragma unroll
            for (int r = 0; r < 4; r++) {
                const int rl = wr * 64 + i * 16 + quad * 4 + r;
                const float mx = fmaxf(red[rl][0], red[rl][1]);
                mloc[i][r] = mx;
                float sm = __expf(acc[i][0][r] - mx) + __expf(acc[i][1][r] - mx) +
                           __expf(acc[i][2][r] - mx) + __expf(acc[i][3][r] - mx);
#pragma unroll
                for (int d = 1; d < 16; d <<= 1) sm += __shfl_xor(sm, d, 64);
                if (lc == 0) redS[rl][wc] = sm;
            }
        __syncthreads();
        if (wc == 0 && lc == 0) {
#pragma unroll
            for (int i = 0; i < 4; i++)
#pragma unroll
                for (int r = 0; r < 4; r++) {
                    const int rl = wr * 64 + i * 16 + quad * 4 + r;
                    const int grow = rowBase + rl;
                    stats_max[blockIdx.x * NB + grow] = mloc[i][r];
                    stats_sum[blockIdx.x * NB + grow] = redS[rl][0] + redS[rl][1];
                }
        }
    } else {
#pragma unroll
        for (int i = 0; i < 4; i++)
#pragma unroll
            for (int r = 0; r < 4; r++) {
                const int grow = rowBase + wr * 64 + i * 16 + quad * 4 + r;
                const float Mv = rowM[grow];
                const float Rv = rowRcpL[grow];
#pragma unroll
                for (int j = 0; j < 4; j++) {
                    const int gcol = colBase + wc * 64 + j * 16 + lc;
                    out[(size_t)grow * NK + gcol] = __expf(acc[i][j][r] - Mv) * Rv;
                }
            }
    }
}

// K4: combine 256 per-colblock stats into per-row (M, 1/L).
// stats layout [colblock][row] -> reads coalesced across threads (one thread/row).
__global__ void combine_stats(const float* __restrict__ sm, const float* __restrict__ ss,
                              float* __restrict__ rowM, float* __restrict__ rowR) {
    const int row = blockIdx.x * 256 + threadIdx.x;   // 8 blocks x 256 = 2048
    float m = -1e30f;
#pragma unroll 8
    for (int c = 0; c < 256; c++) m = fmaxf(m, sm[c * NB + row]);
    float l = 0.f;
#pragma unroll 8
    for (int c = 0; c < 256; c++) l += ss[c * NB + row] * __expf(sm[c * NB + row] - m);
    rowM[row] = m;
    rowR[row] = 1.0f / l;
}

extern "C" void kernel_launch(void* const* d_in, const int* in_sizes, int n_in,
                              void* d_out, int out_size, void* d_ws, size_t ws_size,
                              hipStream_t stream) {
    const float* query  = (const float*)d_in[0];   // [2048][128]
    const float* keys   = (const float*)d_in[1];   // [32768][256] (+-1)
    const float* norms  = (const float*)d_in[2];   // [32768]
    const float* sketch = (const float*)d_in[3];   // [256][128]
    float* out = (float*)d_out;                    // [2048][32768]

    char* ws = (char*)d_ws;
    _Float16* kh   = (_Float16*)(ws);                                   // 16 MB
    _Float16* proj = (_Float16*)(ws + (size_t)16 * 1024 * 1024);        // 1 MB
    float* smax    = (float*)(ws + (size_t)17 * 1024 * 1024);           // 2 MB
    float* ssum    = (float*)(ws + (size_t)19 * 1024 * 1024);           // 2 MB
    float* rowM    = (float*)(ws + (size_t)21 * 1024 * 1024);           // 8 KB
    float* rowR    = (float*)(ws + (size_t)21 * 1024 * 1024 + 8192);    // 8 KB

    hipLaunchKernelGGL(proj_kernel, dim3(NB), dim3(256), 0, stream, query, sketch, proj);
    hipLaunchKernelGGL(cvt_keys, dim3(NK * MM / 4 / 256), dim3(256), 0, stream, keys, kh);
    hipLaunchKernelGGL((gemm_kernel<0>), dim3(NK / 128, NB / 128), dim3(256), 0, stream,
                       proj, kh, norms, smax, ssum, (const float*)nullptr,
                       (const float*)nullptr, (float*)nullptr);
    hipLaunchKernelGGL(combine_stats, dim3(NB / 256), dim3(256), 0, stream,
                       smax, ssum, rowM, rowR);
    hipLaunchKernelGGL((gemm_kernel<1>), dim3(NK / 128, NB / 128), dim3(256), 0, stream,
                       proj, kh, norms, (float*)nullptr, (float*)nullptr, rowM, rowR, out);
}

// Round 2
// 436.322 us; speedup vs baseline: 1.1870x; 1.1870x over previous
//
#include <hip/hip_runtime.h>

// QJLKeyCache: out = softmax_rows(EST * norms[n] * (Q @ S^T) @ K^T)
// B=2048, D=128, M=256, NKEYS=32768.
// Round 2: single fp16 MFMA GEMM that materializes exp(s - m_blocklocal) as
// fp16 scores (128MB) + per-(row,colblock) stats; then a tiny combine and a
// BW-bound elementwise normalize (read fp16 scores, write fp32 out).
// GEMM: BK=64 (4 iters), XOR-swizzled LDS staging (conflict-balanced
// ds_read_b128), swapped MFMA operands so each lane holds 4 consecutive key
// columns -> packed half4 score stores + cheap row-stat reductions.

#define NB 2048
#define DD 128
#define MM 256
#define NK 32768
// sqrt(pi/2)/256
#define EST_CONST 4.8957583489668673e-03f

typedef _Float16 half8 __attribute__((ext_vector_type(8)));
typedef _Float16 half4v __attribute__((ext_vector_type(4)));
typedef float floatx4 __attribute__((ext_vector_type(4)));

__device__ __forceinline__ void async16(const void* g, void* l) {
    __builtin_amdgcn_global_load_lds(
        (const __attribute__((address_space(1))) unsigned int*)g,
        (__attribute__((address_space(3))) unsigned int*)l,
        16, 0, 0);
}

// K1: proj[b][m] = sum_d query[b][d]*sketch[m][d], stored fp16.
__global__ void proj_kernel(const float* __restrict__ query,
                            const float* __restrict__ sketch,
                            _Float16* __restrict__ proj) {
    __shared__ float q[DD];
    const int b = blockIdx.x;
    const int t = threadIdx.x;
    if (t < DD) q[t] = query[b * DD + t];
    __syncthreads();
    const float* srow = sketch + t * DD;   // t = m in [0,256)
    float acc = 0.f;
#pragma unroll
    for (int d = 0; d < DD; d += 4) {
        float4 s4 = *(const float4*)(srow + d);
        acc += s4.x * q[d] + s4.y * q[d + 1] + s4.z * q[d + 2] + s4.w * q[d + 3];
    }
    proj[b * MM + t] = (_Float16)acc;
}

// K2: cached_keys fp32 (+-1) -> fp16 (exact).
__global__ void cvt_keys(const float* __restrict__ keys, _Float16* __restrict__ kh) {
    const int i = blockIdx.x * 256 + threadIdx.x;   // one float4 per thread
    float4 v = ((const float4*)keys)[i];
    half4v h;
    h.x = (_Float16)v.x; h.y = (_Float16)v.y; h.z = (_Float16)v.z; h.w = (_Float16)v.w;
    ((half4v*)kh)[i] = h;
}

// K3: 128x128 tile GEMM, BK=64, fp16 MFMA (keys as FIRST operand so D's
// reg-index r walks key columns). Epilogue: per-row block-local max (mcb),
// e = exp(s - mcb) stored fp16 (packed half4), per-row sumexp (lcb), stats
// written as [row][256] for the combine/normalize passes.
__global__ __launch_bounds__(256, 3)
void score_kernel(const _Float16* __restrict__ proj,   // [2048][256]
                  const _Float16* __restrict__ kh,     // [32768][256]
                  const float* __restrict__ key_norms,
                  _Float16* __restrict__ scores,       // [2048][32768]
                  float* __restrict__ stats_max,       // [2048][256]
                  float* __restrict__ stats_sum) {     // [2048][256]
    __shared__ __align__(16) _Float16 sQ[128 * 64];
    __shared__ __align__(16) _Float16 sK[128 * 64];
    __shared__ float red[128][2];
    __shared__ float redS[128][2];

    const int tid  = threadIdx.x;
    const int lane = tid & 63;
    const int wave = tid >> 6;
    const int quad = lane >> 4;
    const int lc   = lane & 15;
    const int wb   = wave >> 1;   // b-row 64-strip
    const int wn   = wave & 1;    // key-col 64-strip
    const int rowBase = blockIdx.x * 128;   // batch rows
    const int cb      = blockIdx.y;         // key col-block
    const int colBase = cb * 128;

    floatx4 acc[4][4];   // [ib][in]: C[b=wb*64+ib*16+lc][n=wn*64+in*16+quad*4+r]
#pragma unroll
    for (int i = 0; i < 4; i++)
#pragma unroll
        for (int j = 0; j < 4; j++) acc[i][j] = (floatx4){0.f, 0.f, 0.f, 0.f};

    // Staging: chunk c in [0,1024): LDS slot = c*16B (wave-uniform + lane*16),
    // holds global (row=c>>3, seg=(c&7)^(row&7)) -- XOR swizzle balances the
    // ds_read_b128 bank pattern for the 128B row stride.
    const _Float16* gQ[4];
    const _Float16* gK[4];
    int ldsOff[4];
#pragma unroll
    for (int p = 0; p < 4; p++) {
        const int c = p * 256 + tid;
        const int row = c >> 3;
        const int seg = (c & 7) ^ (row & 7);
        gQ[p] = proj + (rowBase + row) * MM + seg * 8;
        gK[p] = kh + (colBase + row) * MM + seg * 8;
        ldsOff[p] = c * 8;
    }

    for (int k0 = 0; k0 < MM; k0 += 64) {
        __syncthreads();
#pragma unroll
        for (int p = 0; p < 4; p++) {
            async16(gQ[p] + k0, &sQ[ldsOff[p]]);
            async16(gK[p] + k0, &sK[ldsOff[p]]);
        }
        __syncthreads();
#pragma unroll
        for (int kk = 0; kk < 2; kk++) {
            const int segSel = ((kk * 4 + quad) ^ (lc & 7)) * 8;
            half8 kf[4], qf[4];
#pragma unroll
            for (int s = 0; s < 4; s++) {
                kf[s] = *(const half8*)&sK[(wn * 64 + s * 16 + lc) * 64 + segSel];
                qf[s] = *(const half8*)&sQ[(wb * 64 + s * 16 + lc) * 64 + segSel];
            }
#pragma unroll
            for (int ib = 0; ib < 4; ib++)
#pragma unroll
                for (int in = 0; in < 4; in++)
                    acc[ib][in] = __builtin_amdgcn_mfma_f32_16x16x32_f16(
                        kf[in], qf[ib], acc[ib][in], 0, 0, 0);
        }
    }

    // scale: s = EST * norm[n] * inner ; n varies with (in, quad, r)
#pragma unroll
    for (int in = 0; in < 4; in++) {
        const float4 nrm = *(const float4*)&key_norms[colBase + wn * 64 + in * 16 + quad * 4];
#pragma unroll
        for (int ib = 0; ib < 4; ib++) {
            acc[ib][in][0] *= EST_CONST * nrm.x;
            acc[ib][in][1] *= EST_CONST * nrm.y;
            acc[ib][in][2] *= EST_CONST * nrm.z;
            acc[ib][in][3] *= EST_CONST * nrm.w;
        }
    }

    // per-row (128-col block-local) max; row owned by lane lc (dup over quads)
    float mcb[4];
#pragma unroll
    for (int ib = 0; ib < 4; ib++) {
        float mx = -1e30f;
#pragma unroll
        for (int in = 0; in < 4; in++)
#pragma unroll
            for (int r = 0; r < 4; r++) mx = fmaxf(mx, acc[ib][in][r]);
        mx = fmaxf(mx, __shfl_xor(mx, 16, 64));
        mx = fmaxf(mx, __shfl_xor(mx, 32, 64));
        if (quad == 0) red[wb * 64 + ib * 16 + lc][wn] = mx;
    }
    __syncthreads();
#pragma unroll
    for (int ib = 0; ib < 4; ib++) {
        const int rl = wb * 64 + ib * 16 + lc;
        mcb[ib] = fmaxf(red[rl][0], red[rl][1]);
    }
    // e = exp(s - mcb), per-row partial sum
#pragma unroll
    for (int ib = 0; ib < 4; ib++) {
        float sm = 0.f;
#pragma unroll
        for (int in = 0; in < 4; in++)
#pragma unroll
            for (int r = 0; r < 4; r++) {
                const float e = __expf(acc[ib][in][r] - mcb[ib]);
                acc[ib][in][r] = e;
                sm += e;
            }
        sm += __shfl_xor(sm, 16, 64);
        sm += __shfl_xor(sm, 32, 64);
        if (quad == 0) redS[wb * 64 + ib * 16 + lc][wn] = sm;
    }
    // packed half4 score stores (4 consecutive key cols per lane)
#pragma unroll
    for (int ib = 0; ib < 4; ib++) {
        const size_t rowOff = (size_t)(rowBase + wb * 64 + ib * 16 + lc) * NK;
#pragma unroll
        for (int in = 0; in < 4; in++) {
            half4v h;
            h.x = (_Float16)acc[ib][in][0];
            h.y = (_Float16)acc[ib][in][1];
            h.z = (_Float16)acc[ib][in][2];
            h.w = (_Float16)acc[ib][in][3];
            *(half4v*)&scores[rowOff + colBase + wn * 64 + in * 16 + quad * 4] = h;
        }
    }
    __syncthreads();
    if (wn == 0 && quad == 0) {
#pragma unroll
        for (int ib = 0; ib < 4; ib++) {
            const int rl = wb * 64 + ib * 16 + lc;
            const int grow = rowBase + rl;
            stats_max[grow * 256 + cb] = mcb[ib];
            stats_sum[grow * 256 + cb] = redS[rl][0] + redS[rl][1];
        }
    }
}

// K4: per-row combine of 256 (m, l) -> (M, 1/L). One wave per row;
// one float4 load per lane per array.
__global__ void combine_stats(const float* __restrict__ smax, const float* __restrict__ ssum,
                              float* __restrict__ rowM, float* __restrict__ rowR) {
    const int lane = threadIdx.x & 63;
    const int row = blockIdx.x * 4 + (threadIdx.x >> 6);
    const float4 mv = ((const float4*)(smax + row * 256))[lane];
    float m = fmaxf(fmaxf(mv.x, mv.y), fmaxf(mv.z, mv.w));
#pragma unroll
    for (int d = 1; d < 64; d <<= 1) m = fmaxf(m, __shfl_xor(m, d, 64));
    const float4 sv = ((const float4*)(ssum + row * 256))[lane];
    float l = sv.x * __expf(mv.x - m) + sv.y * __expf(mv.y - m) +
              sv.z * __expf(mv.z - m) + sv.w * __expf(mv.w - m);
#pragma unroll
    for (int d = 1; d < 64; d <<= 1) l += __shfl_xor(l, d, 64);
    if (lane == 0) {
        rowM[row] = m;
        rowR[row] = 1.0f / l;
    }
}

// K5: out[b][n] = scores[b][n] * exp(mcb(b, n>>7) - M_b) / L_b.
// Pure BW: half8 read + 2x float4 write per thread.
__global__ __launch_bounds__(256)
void norm_kernel(const _Float16* __restrict__ scores,
                 const float* __restrict__ smax,
                 const float* __restrict__ rowM, const float* __restrict__ rowR,
                 float* __restrict__ out) {
    const int idx = blockIdx.x * 256 + threadIdx.x;   // 8M threads
    const int row = idx >> 12;                        // 4096 threads per row
    const int c8 = (idx & 4095) << 3;
    const float scale = __expf(smax[row * 256 + (c8 >> 7)] - rowM[row]) * rowR[row];
    const half8 s = *(const half8*)(scores + ((size_t)row << 15) + c8);
    float4 o0, o1;
    o0.x = (float)s[0] * scale; o0.y = (float)s[1] * scale;
    o0.z = (float)s[2] * scale; o0.w = (float)s[3] * scale;
    o1.x = (float)s[4] * scale; o1.y = (float)s[5] * scale;
    o1.z = (float)s[6] * scale; o1.w = (float)s[7] * scale;
    float4* op = (float4*)(out + ((size_t)row << 15) + c8);
    op[0] = o0;
    op[1] = o1;
}

extern "C" void kernel_launch(void* const* d_in, const int* in_sizes, int n_in,
                              void* d_out, int out_size, void* d_ws, size_t ws_size,
                              hipStream_t stream) {
    const float* query  = (const float*)d_in[0];   // [2048][128]
    const float* keys   = (const float*)d_in[1];   // [32768][256] (+-1)
    const float* norms  = (const float*)d_in[2];   // [32768]
    const float* sketch = (const float*)d_in[3];   // [256][128]
    float* out = (float*)d_out;                    // [2048][32768]

    char* ws = (char*)d_ws;
    const size_t MB = 1024 * 1024;
    _Float16* kh     = (_Float16*)(ws);                     // 16 MB
    _Float16* proj   = (_Float16*)(ws + 16 * MB);           // 1 MB
    _Float16* scores = (_Float16*)(ws + 17 * MB);           // 128 MB
    float* smax      = (float*)(ws + 145 * MB);             // 2 MB
    float* ssum      = (float*)(ws + 147 * MB);             // 2 MB
    float* rowM      = (float*)(ws + 149 * MB);             // 8 KB
    float* rowR      = (float*)(ws + 149 * MB + 8192);      // 8 KB

    hipLaunchKernelGGL(proj_kernel, dim3(NB), dim3(256), 0, stream, query, sketch, proj);
    hipLaunchKernelGGL(cvt_keys, dim3(NK * MM / 4 / 256), dim3(256), 0, stream, keys, kh);
    hipLaunchKernelGGL(score_kernel, dim3(NB / 128, NK / 128), dim3(256), 0, stream,
                       proj, kh, norms, scores, smax, ssum);
    hipLaunchKernelGGL(combine_stats, dim3(NB / 4), dim3(256), 0, stream,
                       smax, ssum, rowM, rowR);
    hipLaunchKernelGGL(norm_kernel, dim3((NB * NK / 8) / 256), dim3(256), 0, stream,
                       scores, smax, rowM, rowR, out);
}

// Round 3
// 403.370 us; speedup vs baseline: 1.2839x; 1.0817x over previous
//
#include <hip/hip_runtime.h>

// QJLKeyCache: out = softmax_rows(EST * norms[n] * (Q @ S^T) @ K^T)
// B=2048, D=128, M=256, NKEYS=32768.
// Round 3: fix VMEM transaction efficiency.
//  - score GEMM epilogue: LDS-transpose the C tile -> fully coalesced 16B/lane
//    fp16 stores (was 32B-granule scatter across 64KB-strided rows).
//  - grid order: blockIdx.x = key colblock so each XCD's L2 owns a fixed 2MB
//    slice of the fp16 keys across all 16 row-block sweeps (keys hit HBM once).
//  - norm: 1 half4 read + 1 contiguous float4 nontemporal store per thread;
//    per-(row,cb) scale precomputed in combine (no expf / extra loads in the
//    256MB streaming pass).

#define NB 2048
#define DD 128
#define MM 256
#define NK 32768
// sqrt(pi/2)/256
#define EST_CONST 4.8957583489668673e-03f

typedef _Float16 half8 __attribute__((ext_vector_type(8)));
typedef _Float16 half4v __attribute__((ext_vector_type(4)));
typedef float floatx4 __attribute__((ext_vector_type(4)));

__device__ __forceinline__ void async16(const void* g, void* l) {
    __builtin_amdgcn_global_load_lds(
        (const __attribute__((address_space(1))) unsigned int*)g,
        (__attribute__((address_space(3))) unsigned int*)l,
        16, 0, 0);
}

// K1: proj[b][m] = sum_d query[b][d]*sketch[m][d], stored fp16.
__global__ void proj_kernel(const float* __restrict__ query,
                            const float* __restrict__ sketch,
                            _Float16* __restrict__ proj) {
    __shared__ float q[DD];
    const int b = blockIdx.x;
    const int t = threadIdx.x;
    if (t < DD) q[t] = query[b * DD + t];
    __syncthreads();
    const float* srow = sketch + t * DD;   // t = m in [0,256)
    float acc = 0.f;
#pragma unroll
    for (int d = 0; d < DD; d += 4) {
        float4 s4 = *(const float4*)(srow + d);
        acc += s4.x * q[d] + s4.y * q[d + 1] + s4.z * q[d + 2] + s4.w * q[d + 3];
    }
    proj[b * MM + t] = (_Float16)acc;
}

// K2: cached_keys fp32 (+-1) -> fp16 (exact).
__global__ void cvt_keys(const float* __restrict__ keys, _Float16* __restrict__ kh) {
    const int i = blockIdx.x * 256 + threadIdx.x;   // one float4 per thread
    float4 v = ((const float4*)keys)[i];
    half4v h;
    h.x = (_Float16)v.x; h.y = (_Float16)v.y; h.z = (_Float16)v.z; h.w = (_Float16)v.w;
    ((half4v*)kh)[i] = h;
}

// K3: 128x128 tile GEMM, BK=64, fp16 MFMA, keys as first operand (lane's 4
// C-regs walk 4 consecutive key cols). Epilogue: block-local max, exp, stats,
// LDS transpose (row stride 136 halves: bank-balanced b64 write + b128 read),
// coalesced fp16 score stores.
__global__ __launch_bounds__(256, 3)
void score_kernel(const _Float16* __restrict__ proj,   // [2048][256]
                  const _Float16* __restrict__ kh,     // [32768][256]
                  const float* __restrict__ key_norms,
                  _Float16* __restrict__ scores,       // [2048][32768]
                  float* __restrict__ stats_max,       // [2048][256]
                  float* __restrict__ stats_sum) {     // [2048][256]
    __shared__ __align__(16) _Float16 smem[17408];   // 34816B: sQ+sK / sT(128x136)
    __shared__ float red[128][2];
    __shared__ float redS[128][2];
    _Float16* sQ = smem;
    _Float16* sK = smem + 8192;

    const int tid  = threadIdx.x;
    const int lane = tid & 63;
    const int wave = tid >> 6;
    const int quad = lane >> 4;
    const int lc   = lane & 15;
    const int wb   = wave >> 1;   // b-row 64-strip
    const int wn   = wave & 1;    // key-col 64-strip
    const int cb      = blockIdx.x;         // key col-block (fastest -> XCD owns keys)
    const int colBase = cb * 128;
    const int rowBase = blockIdx.y * 128;   // batch rows

    floatx4 acc[4][4];   // [ib][in]: C[b=wb*64+ib*16+lc][n=wn*64+in*16+quad*4+r]
#pragma unroll
    for (int i = 0; i < 4; i++)
#pragma unroll
        for (int j = 0; j < 4; j++) acc[i][j] = (floatx4){0.f, 0.f, 0.f, 0.f};

    // Staging: chunk c in [0,1024): LDS slot c*16B (wave-uniform + lane*16),
    // holds global (row=c>>3, seg=(c&7)^(row&7)) -- XOR swizzle balances the
    // ds_read_b128 bank pattern for the 128B row stride.
    const _Float16* gQ[4];
    const _Float16* gK[4];
    int ldsOff[4];
#pragma unroll
    for (int p = 0; p < 4; p++) {
        const int c = p * 256 + tid;
        const int row = c >> 3;
        const int seg = (c & 7) ^ (row & 7);
        gQ[p] = proj + (rowBase + row) * MM + seg * 8;
        gK[p] = kh + (colBase + row) * MM + seg * 8;
        ldsOff[p] = c * 8;
    }

    for (int k0 = 0; k0 < MM; k0 += 64) {
        __syncthreads();
#pragma unroll
        for (int p = 0; p < 4; p++) {
            async16(gQ[p] + k0, &sQ[ldsOff[p]]);
            async16(gK[p] + k0, &sK[ldsOff[p]]);
        }
        __syncthreads();
#pragma unroll
        for (int kk = 0; kk < 2; kk++) {
            const int segSel = ((kk * 4 + quad) ^ (lc & 7)) * 8;
            half8 kf[4], qf[4];
#pragma unroll
            for (int s = 0; s < 4; s++) {
                kf[s] = *(const half8*)&sK[(wn * 64 + s * 16 + lc) * 64 + segSel];
                qf[s] = *(const half8*)&sQ[(wb * 64 + s * 16 + lc) * 64 + segSel];
            }
#pragma unroll
            for (int ib = 0; ib < 4; ib++)
#pragma unroll
                for (int in = 0; in < 4; in++)
                    acc[ib][in] = __builtin_amdgcn_mfma_f32_16x16x32_f16(
                        kf[in], qf[ib], acc[ib][in], 0, 0, 0);
        }
    }

    // scale: s = EST * norm[n] * inner ; n varies with (in, quad, r)
#pragma unroll
    for (int in = 0; in < 4; in++) {
        const float4 nrm = *(const float4*)&key_norms[colBase + wn * 64 + in * 16 + quad * 4];
#pragma unroll
        for (int ib = 0; ib < 4; ib++) {
            acc[ib][in][0] *= EST_CONST * nrm.x;
            acc[ib][in][1] *= EST_CONST * nrm.y;
            acc[ib][in][2] *= EST_CONST * nrm.z;
            acc[ib][in][3] *= EST_CONST * nrm.w;
        }
    }

    // per-row (128-col block-local) max; row owned by lane lc (dup over quads)
#pragma unroll
    for (int ib = 0; ib < 4; ib++) {
        float mx = -1e30f;
#pragma unroll
        for (int in = 0; in < 4; in++)
#pragma unroll
            for (int r = 0; r < 4; r++) mx = fmaxf(mx, acc[ib][in][r]);
        mx = fmaxf(mx, __shfl_xor(mx, 16, 64));
        mx = fmaxf(mx, __shfl_xor(mx, 32, 64));
        if (quad == 0) red[wb * 64 + ib * 16 + lc][wn] = mx;
    }
    __syncthreads();   // red visible; all waves past k-loop (smem now dead)
    float mcb[4];
#pragma unroll
    for (int ib = 0; ib < 4; ib++) {
        const int rl = wb * 64 + ib * 16 + lc;
        mcb[ib] = fmaxf(red[rl][0], red[rl][1]);
    }
    // e = exp(s - mcb): partial sums + LDS-transpose write (fp16)
#pragma unroll
    for (int ib = 0; ib < 4; ib++) {
        float sm = 0.f;
#pragma unroll
        for (int in = 0; in < 4; in++) {
            half4v h;
#pragma unroll
            for (int r = 0; r < 4; r++) {
                const float e = __expf(acc[ib][in][r] - mcb[ib]);
                h[r] = (_Float16)e;
                sm += e;
            }
            *(half4v*)&smem[(wb * 64 + ib * 16 + lc) * 136 + wn * 64 + in * 16 + quad * 4] = h;
        }
        sm += __shfl_xor(sm, 16, 64);
        sm += __shfl_xor(sm, 32, 64);
        if (quad == 0) redS[wb * 64 + ib * 16 + lc][wn] = sm;
    }
    __syncthreads();   // sT + redS visible
    if (wn == 0 && quad == 0) {
#pragma unroll
        for (int ib = 0; ib < 4; ib++) {
            const int rl = wb * 64 + ib * 16 + lc;
            const int grow = rowBase + rl;
            stats_max[grow * 256 + cb] = mcb[ib];
            stats_sum[grow * 256 + cb] = redS[rl][0] + redS[rl][1];
        }
    }
    // coalesced score stores: 16B/lane, 256B contiguous per 16 lanes
#pragma unroll
    for (int p = 0; p < 8; p++) {
        const int flat = p * 2048 + tid * 8;
        const int row = flat >> 7;
        const int col = flat & 127;
        half8 v = *(const half8*)&smem[row * 136 + col];
        *(half8*)&scores[(size_t)(rowBase + row) * NK + colBase + col] = v;
    }
}

// K4: per-row combine of 256 (m, l) -> cbscale[row][cb] = exp(m_cb - M)/L.
// One wave per row; one float4 per lane per array; butterfly gives all lanes
// the row max/sum.
__global__ void combine_stats(const float* __restrict__ smax, const float* __restrict__ ssum,
                              float* __restrict__ cbscale) {
    const int lane = threadIdx.x & 63;
    const int row = blockIdx.x * 4 + (threadIdx.x >> 6);
    const float4 mv = ((const float4*)(smax + row * 256))[lane];
    float m = fmaxf(fmaxf(mv.x, mv.y), fmaxf(mv.z, mv.w));
#pragma unroll
    for (int d = 1; d < 64; d <<= 1) m = fmaxf(m, __shfl_xor(m, d, 64));
    const float4 sv = ((const float4*)(ssum + row * 256))[lane];
    float l = sv.x * __expf(mv.x - m) + sv.y * __expf(mv.y - m) +
              sv.z * __expf(mv.z - m) + sv.w * __expf(mv.w - m);
#pragma unroll
    for (int d = 1; d < 64; d <<= 1) l += __shfl_xor(l, d, 64);
    const float rL = 1.0f / l;
    float4 sc;
    sc.x = __expf(mv.x - m) * rL;
    sc.y = __expf(mv.y - m) * rL;
    sc.z = __expf(mv.z - m) * rL;
    sc.w = __expf(mv.w - m) * rL;
    ((float4*)(cbscale + row * 256))[lane] = sc;
}

// K5: out[b][n] = scores[b][n] * cbscale[b][n>>7].
// 1 half4 read + 1 contiguous float4 nontemporal store per thread.
__global__ __launch_bounds__(256)
void norm_kernel(const _Float16* __restrict__ scores,
                 const float* __restrict__ cbscale,
                 float* __restrict__ out) {
    const unsigned idx = blockIdx.x * 256 + threadIdx.x;   // 16M threads
    const int row = idx >> 13;                             // 8192 threads/row
    const int c4 = (idx & 8191) << 2;
    const float scale = cbscale[row * 256 + (c4 >> 7)];
    const half4v s = *(const half4v*)(scores + ((size_t)row << 15) + c4);
    floatx4 o;
    o[0] = (float)s.x * scale;
    o[1] = (float)s.y * scale;
    o[2] = (float)s.z * scale;
    o[3] = (float)s.w * scale;
    __builtin_nontemporal_store(o, (floatx4*)(out + ((size_t)row << 15) + c4));
}

extern "C" void kernel_launch(void* const* d_in, const int* in_sizes, int n_in,
                              void* d_out, int out_size, void* d_ws, size_t ws_size,
                              hipStream_t stream) {
    const float* query  = (const float*)d_in[0];   // [2048][128]
    const float* keys   = (const float*)d_in[1];   // [32768][256] (+-1)
    const float* norms  = (const float*)d_in[2];   // [32768]
    const float* sketch = (const float*)d_in[3];   // [256][128]
    float* out = (float*)d_out;                    // [2048][32768]

    char* ws = (char*)d_ws;
    const size_t MB = 1024 * 1024;
    _Float16* kh     = (_Float16*)(ws);                     // 16 MB
    _Float16* proj   = (_Float16*)(ws + 16 * MB);           // 1 MB
    _Float16* scores = (_Float16*)(ws + 17 * MB);           // 128 MB
    float* smax      = (float*)(ws + 145 * MB);             // 2 MB
    float* ssum      = (float*)(ws + 147 * MB);             // 2 MB
    float* cbscale   = (float*)(ws + 149 * MB);             // 2 MB

    hipLaunchKernelGGL(proj_kernel, dim3(NB), dim3(256), 0, stream, query, sketch, proj);
    hipLaunchKernelGGL(cvt_keys, dim3(NK * MM / 4 / 256), dim3(256), 0, stream, keys, kh);
    hipLaunchKernelGGL(score_kernel, dim3(NK / 128, NB / 128), dim3(256), 0, stream,
                       proj, kh, norms, scores, smax, ssum);
    hipLaunchKernelGGL(combine_stats, dim3(NB / 4), dim3(256), 0, stream,
                       smax, ssum, cbscale);
    hipLaunchKernelGGL(norm_kernel, dim3((NB * NK / 4) / 256), dim3(256), 0, stream,
                       scores, cbscale, out);
}